// Round 11
// baseline (169.120 us; speedup 1.0000x reference)
//
#include <hip/hip_runtime.h>
#include <math.h>

// Problem constants
#define KP   10      // prototypes per side
#define CC   768     // channels
#define NB   8       // batch
#define HW   4096    // 64*64
#define STOT 32768   // NB*HW
#define NS   12      // N_SAMPLES
#define NBLK 256     // k_scores blocks (128 px each)

// Workspace layout (float offsets)
#define WS_CAND  0       // 2 sides x 256 blocks x 12 u64 = 6144 ull = 12288 floats
#define WS_FEATS 12352   // 24*768 floats (pos 12 rows, then neg 12 rows)
#define WS_PFG   30784   // 10*768
#define WS_PBG   38464   // 10*768

typedef unsigned long long ull;
typedef float f2v __attribute__((ext_vector_type(2)));

// Order-preserving float->uint map, packed with ~index for exact
// (value desc, index asc) ordering under unsigned max. Unique per pixel.
__device__ __forceinline__ ull pack_key(float v, int idx) {
    unsigned u = __float_as_uint(v);
    u ^= (unsigned)((int)u >> 31) | 0x80000000u;
    return ((ull)u << 32) | (ull)(0xFFFFFFFFu - (unsigned)idx);
}

// ---------------- K1: scores + per-block top-12 candidates ----------------
// 1024-thread blocks: 16 waves x 48 channels; 2 px/lane (dwordx2 F loads,
// non-temporal, DEPTH-2 prefetch). Protos staged in LDS (ds broadcast reads,
// VMEM pipe carries only F). Final phase selects the block's top-12 per side
// in-kernel -> scores never touch global memory.
__global__ __launch_bounds__(1024) void k_scores(const float* __restrict__ fg,
                                                 const float* __restrict__ bg,
                                                 const float* __restrict__ F,
                                                 const float* __restrict__ M,
                                                 ull* __restrict__ cand) {
    __shared__ float pl[20 * CC];           // 61440 B
    __shared__ float part[8][64][2][21];    // 86016 B
    __shared__ ull wbF[16], wbB[16];
    __shared__ ull winF_sh, winB_sh;

    const int tid  = threadIdx.x;
    const int w    = __builtin_amdgcn_readfirstlane(tid >> 6);  // wave 0..15
    const int lane = tid & 63;
    const int b    = blockIdx.x;            // 0..255
    const int n    = b >> 5;                // 32 blocks per image
    const int hwb  = (b & 31) * 128 + lane * 2;
    const float* fp = F + ((size_t)n * CC) * HW + hwb;
    const int cbase = w * 48;

    // depth-2 prefetch (independent of LDS staging)
    f2v fnA[8], fnB[8];
#pragma unroll
    for (int j = 0; j < 8; ++j)
        fnA[j] = __builtin_nontemporal_load((const f2v*)(fp + (size_t)(cbase + j) * HW));
#pragma unroll
    for (int j = 0; j < 8; ++j)
        fnB[j] = __builtin_nontemporal_load((const f2v*)(fp + (size_t)(cbase + 8 + j) * HW));

    for (int i = tid; i < KP * CC; i += 1024) {
        pl[i]           = fg[i];
        pl[KP * CC + i] = bg[i];
    }
    __syncthreads();

    float afg[2][KP], abg[2][KP], n2[2];
#pragma unroll
    for (int k = 0; k < KP; ++k) { afg[0][k] = 0.f; afg[1][k] = 0.f; abg[0][k] = 0.f; abg[1][k] = 0.f; }
    n2[0] = 0.f; n2[1] = 0.f;

    for (int c0 = 0; c0 < 48; c0 += 8) {
        f2v f[8];
#pragma unroll
        for (int j = 0; j < 8; ++j) { f[j] = fnA[j]; fnA[j] = fnB[j]; }
        if (c0 + 16 < 48) {
#pragma unroll
            for (int j = 0; j < 8; ++j)
                fnB[j] = __builtin_nontemporal_load((const f2v*)(fp + (size_t)(cbase + c0 + 16 + j) * HW));
        }

#pragma unroll
        for (int k = 0; k < KP; ++k) {
            const float4* pq = (const float4*)&pl[k * CC + cbase + c0];
            float4 a = pq[0], c = pq[1];
            float acc0 = afg[0][k], acc1 = afg[1][k];
            acc0 = fmaf(f[0].x, a.x, acc0); acc1 = fmaf(f[0].y, a.x, acc1);
            acc0 = fmaf(f[1].x, a.y, acc0); acc1 = fmaf(f[1].y, a.y, acc1);
            acc0 = fmaf(f[2].x, a.z, acc0); acc1 = fmaf(f[2].y, a.z, acc1);
            acc0 = fmaf(f[3].x, a.w, acc0); acc1 = fmaf(f[3].y, a.w, acc1);
            acc0 = fmaf(f[4].x, c.x, acc0); acc1 = fmaf(f[4].y, c.x, acc1);
            acc0 = fmaf(f[5].x, c.y, acc0); acc1 = fmaf(f[5].y, c.y, acc1);
            acc0 = fmaf(f[6].x, c.z, acc0); acc1 = fmaf(f[6].y, c.z, acc1);
            acc0 = fmaf(f[7].x, c.w, acc0); acc1 = fmaf(f[7].y, c.w, acc1);
            afg[0][k] = acc0; afg[1][k] = acc1;
        }
#pragma unroll
        for (int k = 0; k < KP; ++k) {
            const float4* pq = (const float4*)&pl[(KP + k) * CC + cbase + c0];
            float4 a = pq[0], c = pq[1];
            float acc0 = abg[0][k], acc1 = abg[1][k];
            acc0 = fmaf(f[0].x, a.x, acc0); acc1 = fmaf(f[0].y, a.x, acc1);
            acc0 = fmaf(f[1].x, a.y, acc0); acc1 = fmaf(f[1].y, a.y, acc1);
            acc0 = fmaf(f[2].x, a.z, acc0); acc1 = fmaf(f[2].y, a.z, acc1);
            acc0 = fmaf(f[3].x, a.w, acc0); acc1 = fmaf(f[3].y, a.w, acc1);
            acc0 = fmaf(f[4].x, c.x, acc0); acc1 = fmaf(f[4].y, c.x, acc1);
            acc0 = fmaf(f[5].x, c.y, acc0); acc1 = fmaf(f[5].y, c.y, acc1);
            acc0 = fmaf(f[6].x, c.z, acc0); acc1 = fmaf(f[6].y, c.z, acc1);
            acc0 = fmaf(f[7].x, c.w, acc0); acc1 = fmaf(f[7].y, c.w, acc1);
            abg[0][k] = acc0; abg[1][k] = acc1;
        }
#pragma unroll
        for (int j = 0; j < 8; ++j) {
            n2[0] = fmaf(f[j].x, f[j].x, n2[0]);
            n2[1] = fmaf(f[j].y, f[j].y, n2[1]);
        }
    }

    // fold 16 waves -> 8 slots
    if (w >= 8) {
#pragma unroll
        for (int px = 0; px < 2; ++px) {
#pragma unroll
            for (int k = 0; k < KP; ++k) {
                part[w - 8][lane][px][k]      = afg[px][k];
                part[w - 8][lane][px][10 + k] = abg[px][k];
            }
            part[w - 8][lane][px][20] = n2[px];
        }
    }
    __syncthreads();
    if (w < 8) {
#pragma unroll
        for (int px = 0; px < 2; ++px) {
#pragma unroll
            for (int k = 0; k < KP; ++k) {
                part[w][lane][px][k]      += afg[px][k];
                part[w][lane][px][10 + k] += abg[px][k];
            }
            part[w][lane][px][20] += n2[px];
        }
    }
    __syncthreads();

    // threads 0..127: finalize own pixel's two scores -> packed keys
    ull kf = 0ull, kb = 0ull;
    if (tid < 128) {
        const int lane2 = tid >> 1, j = tid & 1;
        float vals[21];
#pragma unroll
        for (int q = 0; q < 21; ++q) {
            float acc = 0.f;
#pragma unroll
            for (int ss = 0; ss < 8; ++ss) acc += part[ss][lane2][j][q];
            vals[q] = acc;
        }
        float mfg = vals[0], mbg = vals[10];
#pragma unroll
        for (int k = 1; k < KP; ++k) { mfg = fmaxf(mfg, vals[k]); mbg = fmaxf(mbg, vals[10 + k]); }
        float nc = fmaxf(sqrtf(vals[20]), 1e-8f);
        int sp = b * 128 + tid;
        float m = fminf(fmaxf(M[sp], 0.f), 1.f);
        float s_fg = (1.f - mfg / nc) * m;
        float s_bg = (1.f - mbg / nc) * (1.f - m);
        kf = pack_key(s_fg, sp);
        kb = pack_key(s_bg, sp);
    }

    // block-local top-12 per side (keys unique -> exact clear)
    for (int r = 0; r < NS; ++r) {
        ull bf = kf, bb = kb;
#pragma unroll
        for (int m2 = 1; m2 < 64; m2 <<= 1) {
            ull of = __shfl_xor(bf, m2, 64);
            ull ob = __shfl_xor(bb, m2, 64);
            bf = (of > bf) ? of : bf;
            bb = (ob > bb) ? ob : bb;
        }
        if (lane == 0) { wbF[w] = bf; wbB[w] = bb; }
        __syncthreads();
        if (tid == 0) {
            ull mf = wbF[0], mb = wbB[0];
#pragma unroll
            for (int ww = 1; ww < 16; ++ww) {
                mf = (wbF[ww] > mf) ? wbF[ww] : mf;
                mb = (wbB[ww] > mb) ? wbB[ww] : mb;
            }
            winF_sh = mf; winB_sh = mb;
            cand[b * NS + r]               = mf;
            cand[NBLK * NS + b * NS + r]   = mb;
        }
        __syncthreads();
        if (kf == winF_sh) kf = 0ull;
        if (kb == winB_sh) kb = 0ull;
    }
}

// ---------------- K2: global top-12 merge + gather + normalize (2 blocks) ----
__global__ __launch_bounds__(1024) void k_topk2g(const ull* __restrict__ cand,
                                                 const float* __restrict__ F,
                                                 float* __restrict__ feats) {
    const int side = blockIdx.x;
    const int tid  = threadIdx.x;
    const int wave = __builtin_amdgcn_readfirstlane(tid >> 6);  // 0..15
    const int lane = tid & 63;

    __shared__ ull   wbest[16];
    __shared__ ull   win_sh;
    __shared__ int   seli[NS];
    __shared__ float gl[NS * CC];   // 36 KB

    const ull* cs = cand + side * (NBLK * NS);
    ull k0 = cs[tid];
    ull k1 = cs[1024 + tid];
    ull k2 = cs[2048 + tid];

    for (int r = 0; r < NS; ++r) {
        ull b = (k0 > k1) ? k0 : k1;
        b = (k2 > b) ? k2 : b;
#pragma unroll
        for (int m2 = 1; m2 < 64; m2 <<= 1) {
            ull o = __shfl_xor(b, m2, 64);
            b = (o > b) ? o : b;
        }
        if (lane == 0) wbest[wave] = b;
        __syncthreads();
        if (tid == 0) {
            ull m = wbest[0];
#pragma unroll
            for (int ww = 1; ww < 16; ++ww) m = (wbest[ww] > m) ? wbest[ww] : m;
            win_sh = m;
            seli[r] = (int)(0xFFFFFFFFu - (unsigned)(m & 0xFFFFFFFFull));
        }
        __syncthreads();
        ull win = win_sh;
        if (k0 == win) k0 = 0ull;
        if (k1 == win) k1 = 0ull;
        if (k2 == win) k2 = 0ull;
    }

    // gather 12 rows x 768 channels into LDS
    for (int i = tid; i < NS * CC; i += 1024) {
        int srow = i / CC, c = i - srow * CC;
        int sp = seli[srow];
        int nn = sp >> 12, hh = sp & 4095;
        gl[i] = F[((size_t)nn * CC + c) * HW + hh];
    }
    __syncthreads();

    // row-normalize: wave r (<12) handles row r; write to global feats
    if (wave < NS) {
        float ssq = 0.f;
#pragma unroll
        for (int j = 0; j < 12; ++j) { float v = gl[wave * CC + j * 64 + lane]; ssq = fmaf(v, v, ssq); }
#pragma unroll
        for (int m2 = 1; m2 < 64; m2 <<= 1) ssq += __shfl_xor(ssq, m2, 64);
        float inv = 1.f / fmaxf(sqrtf(ssq), 1e-8f);
#pragma unroll
        for (int j = 0; j < 12; ++j)
            feats[side * (NS * CC) + wave * CC + j * 64 + lane] = gl[wave * CC + j * 64 + lane] * inv;
    }
}

// ---------------- K3: refinement (one wave per prototype) + blend epilogue ----
__global__ __launch_bounds__(640) void k_refine(const float* __restrict__ feats_all,
                                                const float* __restrict__ fg,
                                                const float* __restrict__ bg,
                                                float* __restrict__ pfg,
                                                float* __restrict__ pbg,
                                                float* __restrict__ out) {
    __shared__ float fe[NS * CC];
    __shared__ float dots[NS][KP];
    __shared__ int   assign[NS];

    const int tid  = threadIdx.x;
    const int k    = __builtin_amdgcn_readfirstlane(tid >> 6);   // wave id = proto id
    const int lane = tid & 63;
    const float* feats = feats_all + blockIdx.x * (NS * CC);
    const float* p0    = (blockIdx.x == 0) ? fg : bg;
    float* pout        = (blockIdx.x == 0) ? pfg : pbg;

    for (int i = tid; i < NS * CC; i += 640) fe[i] = feats[i];
    float p[12];
#pragma unroll
    for (int j = 0; j < 12; ++j) p[j] = p0[k * CC + j * 64 + lane];
    __syncthreads();

    for (int it = 0; it < 10; ++it) {
        float step = 0.1f / (1.0f + 0.5f * (float)it);

        float d[NS];
#pragma unroll
        for (int s = 0; s < NS; ++s) d[s] = 0.f;
#pragma unroll
        for (int j = 0; j < 12; ++j) {
            float pvj = p[j];
#pragma unroll
            for (int s = 0; s < NS; ++s) d[s] = fmaf(fe[s * CC + j * 64 + lane], pvj, d[s]);
        }
#pragma unroll
        for (int s = 0; s < NS; ++s) {
#pragma unroll
            for (int m2 = 1; m2 < 64; m2 <<= 1) d[s] += __shfl_xor(d[s], m2, 64);
        }
        if (lane == 0) {
#pragma unroll
            for (int s = 0; s < NS; ++s) dots[s][k] = d[s];
        }
        __syncthreads();

        if (tid < NS) {
            float bv = dots[tid][0]; int bk = 0;
#pragma unroll
            for (int kk = 1; kk < KP; ++kk) { float v = dots[tid][kk]; if (v > bv) { bv = v; bk = kk; } }
            assign[tid] = bk;
        }
        __syncthreads();

        int a[NS]; int cnt = 0;
#pragma unroll
        for (int s = 0; s < NS; ++s) { a[s] = assign[s]; cnt += (a[s] == k) ? 1 : 0; }

        if (cnt > 0) {
            float mac[12];
#pragma unroll
            for (int j = 0; j < 12; ++j) mac[j] = 0.f;
#pragma unroll
            for (int s = 0; s < NS; ++s) {
                if (a[s] == k) {   // wave-uniform branch
#pragma unroll
                    for (int j = 0; j < 12; ++j) mac[j] += fe[s * CC + j * 64 + lane];
                }
            }
            float fcnt = (float)cnt;
            float v[12]; float ss = 0.f;
#pragma unroll
            for (int j = 0; j < 12; ++j) {
                float mean = mac[j] / fcnt;
                v[j] = (1.0f - step) * p[j] + step * mean;
                ss = fmaf(v[j], v[j], ss);
            }
#pragma unroll
            for (int m2 = 1; m2 < 64; m2 <<= 1) ss += __shfl_xor(ss, m2, 64);
            float inv = 1.f / fmaxf(sqrtf(ss), 1e-8f);
#pragma unroll
            for (int j = 0; j < 12; ++j) p[j] = v[j] * inv;
        }
    }

    // publish refined protos for the loss kernel
#pragma unroll
    for (int j = 0; j < 12; ++j) pout[k * CC + j * 64 + lane] = p[j];

    // blend epilogue: out row = safe_norm(0.7*p0 + 0.3*p)
    float vv[12]; float ss2 = 0.f;
#pragma unroll
    for (int j = 0; j < 12; ++j) {
        vv[j] = (1.0f - 0.3f) * p0[k * CC + j * 64 + lane] + 0.3f * p[j];
        ss2 = fmaf(vv[j], vv[j], ss2);
    }
#pragma unroll
    for (int m2 = 1; m2 < 64; m2 <<= 1) ss2 += __shfl_xor(ss2, m2, 64);
    float inv2 = 1.f / fmaxf(sqrtf(ss2), 1e-8f);
    float* orow = out + 1 + (blockIdx.x * KP + k) * CC;
#pragma unroll
    for (int j = 0; j < 12; ++j) orow[j * 64 + lane] = vv[j] * inv2;
}

// ---------------- K4: loss (1 block) ----------------
__global__ __launch_bounds__(256) void k_loss(const float* __restrict__ feats,
                                              const float* __restrict__ pfg,
                                              const float* __restrict__ pbg,
                                              float* __restrict__ out) {
    __shared__ float dots3[NS * 30];   // [s][g*10+k]: g=0 pos@pfg, g=1 neg@pfg, g=2 pos@pbg
    __shared__ float mp[NS], mn[NS], infon[NS];
    int tid = threadIdx.x, wave = tid >> 6, lane = tid & 63;

    for (int pid = wave; pid < 360; pid += 4) {
        int g = pid / 120, rr = pid % 120, s = rr / KP, k = rr % KP;
        const float4* a4 = (const float4*)(feats + ((g == 1 ? NS + s : s) * CC) + lane * 12);
        const float4* b4 = (const float4*)((g == 2 ? pbg : pfg) + k * CC + lane * 12);
        float acc = 0.f;
#pragma unroll
        for (int j = 0; j < 3; ++j) {
            float4 a = a4[j], b = b4[j];
            acc += a.x * b.x + a.y * b.y + a.z * b.z + a.w * b.w;
        }
#pragma unroll
        for (int m2 = 1; m2 < 64; m2 <<= 1) acc += __shfl_xor(acc, m2, 64);
        if (lane == 0) dots3[s * 30 + g * 10 + k] = acc;
    }
    __syncthreads();

    if (tid < NS) {
        const float* d = &dots3[tid * 30];
        float maxp = d[0], maxn = d[10];
#pragma unroll
        for (int k = 1; k < KP; ++k) { maxp = fmaxf(maxp, d[k]); maxn = fmaxf(maxn, d[10 + k]); }
        mp[tid] = maxp; mn[tid] = maxn;

        float x[KP], y[KP];
#pragma unroll
        for (int k = 0; k < KP; ++k) { x[k] = d[k] / 0.07f; y[k] = d[20 + k] / 0.07f; }
        float m10 = x[0];
#pragma unroll
        for (int k = 1; k < KP; ++k) m10 = fmaxf(m10, x[k]);
        float se = 0.f;
#pragma unroll
        for (int k = 0; k < KP; ++k) se += expf(x[k] - m10);
        float numer = logf(se) + m10;
        float m20 = m10;
#pragma unroll
        for (int k = 0; k < KP; ++k) m20 = fmaxf(m20, y[k]);
        float se2 = 0.f;
#pragma unroll
        for (int k = 0; k < KP; ++k) se2 += expf(x[k] - m20);
#pragma unroll
        for (int k = 0; k < KP; ++k) se2 += expf(y[k] - m20);
        float denom = logf(se2) + m20;
        infon[tid] = numer - denom;
    }
    __syncthreads();
    if (tid == 0) {
        float sp = 0.f, sn = 0.f, si = 0.f;
        for (int s = 0; s < NS; ++s) { sp += mp[s]; sn += mn[s]; si += infon[s]; }
        sp /= 12.f; sn /= 12.f; si /= 12.f;
        float loss = fmaxf(0.2f + sn - sp, 0.f) + 0.25f * (-si);
        out[0] = loss;
    }
}

extern "C" void kernel_launch(void* const* d_in, const int* in_sizes, int n_in,
                              void* d_out, int out_size, void* d_ws, size_t ws_size,
                              hipStream_t stream) {
    const float* fg = (const float*)d_in[0];   // [10,768]
    const float* bg = (const float*)d_in[1];   // [10,768]
    const float* F  = (const float*)d_in[2];   // [8,768,64,64]
    const float* M  = (const float*)d_in[3];   // [8,1,64,64]
    float* out = (float*)d_out;                // [1 + 7680 + 7680]

    float* w    = (float*)d_ws;
    ull*   cand = (ull*)(w + WS_CAND);
    float* fea  = w + WS_FEATS;
    float* pfg  = w + WS_PFG;
    float* pbg  = w + WS_PBG;

    k_scores<<<NBLK, 1024, 0, stream>>>(fg, bg, F, M, cand);
    k_topk2g<<<2, 1024, 0, stream>>>(cand, F, fea);
    k_refine<<<2, 640, 0, stream>>>(fea, fg, bg, pfg, pbg, out);
    k_loss  <<<1, 256, 0, stream>>>(fea, pfg, pbg, out);
}

// Round 12
// 146.362 us; speedup vs baseline: 1.1555x; 1.1555x over previous
//
#include <hip/hip_runtime.h>
#include <math.h>

// Problem constants
#define KP   10      // prototypes per side
#define CC   768     // channels
#define NB   8       // batch
#define HW   4096    // 64*64
#define STOT 32768   // NB*HW
#define NS   12      // N_SAMPLES
#define NBLK 256     // k_scores blocks (128 px each)

// Workspace layout (float offsets)
#define WS_CAND  0       // 2 sides x 256 blocks x 12 u64 = 6144 ull = 12288 floats
#define WS_FEATS 12352   // 24*768 floats (pos 12 rows, then neg 12 rows)
#define WS_PFG   30784   // 10*768
#define WS_PBG   38464   // 10*768

typedef unsigned long long ull;
typedef float f2v __attribute__((ext_vector_type(2)));

// Order-preserving float->uint map, packed with ~index for exact
// (value desc, index asc) ordering under unsigned max. Unique per pixel;
// real keys are always > 0 (sign-flip sets the top bit), so 0 = empty.
__device__ __forceinline__ ull pack_key(float v, int idx) {
    unsigned u = __float_as_uint(v);
    u ^= (unsigned)((int)u >> 31) | 0x80000000u;
    return ((ull)u << 32) | (ull)(0xFFFFFFFFu - (unsigned)idx);
}

// ---------------- K1: scores + per-block top-12 candidates ----------------
// 1024-thread blocks: 16 waves x 48 channels; 2 px/lane (dwordx2 nt F loads,
// depth-2 prefetch). Protos staged in LDS. Selection phase: keys to LDS,
// then wave 0 (fg) / wave 1 (bg) each do 12 rounds of barrier-free in-wave
// butterfly max -- no block barriers in the selection loop (R11's mistake).
__global__ __launch_bounds__(1024) void k_scores(const float* __restrict__ fg,
                                                 const float* __restrict__ bg,
                                                 const float* __restrict__ F,
                                                 const float* __restrict__ M,
                                                 ull* __restrict__ cand) {
    __shared__ float pl[20 * CC];           // 61440 B
    __shared__ float part[8][64][2][21];    // 86016 B
    __shared__ ull kfl[128], kbl[128];      // 2048 B

    const int tid  = threadIdx.x;
    const int w    = __builtin_amdgcn_readfirstlane(tid >> 6);  // wave 0..15
    const int lane = tid & 63;
    const int b    = blockIdx.x;            // 0..255
    const int n    = b >> 5;                // 32 blocks per image
    const int hwb  = (b & 31) * 128 + lane * 2;
    const float* fp = F + ((size_t)n * CC) * HW + hwb;
    const int cbase = w * 48;

    // depth-2 prefetch (independent of LDS staging)
    f2v fnA[8], fnB[8];
#pragma unroll
    for (int j = 0; j < 8; ++j)
        fnA[j] = __builtin_nontemporal_load((const f2v*)(fp + (size_t)(cbase + j) * HW));
#pragma unroll
    for (int j = 0; j < 8; ++j)
        fnB[j] = __builtin_nontemporal_load((const f2v*)(fp + (size_t)(cbase + 8 + j) * HW));

    for (int i = tid; i < KP * CC; i += 1024) {
        pl[i]           = fg[i];
        pl[KP * CC + i] = bg[i];
    }
    __syncthreads();

    float afg[2][KP], abg[2][KP], n2[2];
#pragma unroll
    for (int k = 0; k < KP; ++k) { afg[0][k] = 0.f; afg[1][k] = 0.f; abg[0][k] = 0.f; abg[1][k] = 0.f; }
    n2[0] = 0.f; n2[1] = 0.f;

    for (int c0 = 0; c0 < 48; c0 += 8) {
        f2v f[8];
#pragma unroll
        for (int j = 0; j < 8; ++j) { f[j] = fnA[j]; fnA[j] = fnB[j]; }
        if (c0 + 16 < 48) {
#pragma unroll
            for (int j = 0; j < 8; ++j)
                fnB[j] = __builtin_nontemporal_load((const f2v*)(fp + (size_t)(cbase + c0 + 16 + j) * HW));
        }

#pragma unroll
        for (int k = 0; k < KP; ++k) {
            const float4* pq = (const float4*)&pl[k * CC + cbase + c0];
            float4 a = pq[0], c = pq[1];
            float acc0 = afg[0][k], acc1 = afg[1][k];
            acc0 = fmaf(f[0].x, a.x, acc0); acc1 = fmaf(f[0].y, a.x, acc1);
            acc0 = fmaf(f[1].x, a.y, acc0); acc1 = fmaf(f[1].y, a.y, acc1);
            acc0 = fmaf(f[2].x, a.z, acc0); acc1 = fmaf(f[2].y, a.z, acc1);
            acc0 = fmaf(f[3].x, a.w, acc0); acc1 = fmaf(f[3].y, a.w, acc1);
            acc0 = fmaf(f[4].x, c.x, acc0); acc1 = fmaf(f[4].y, c.x, acc1);
            acc0 = fmaf(f[5].x, c.y, acc0); acc1 = fmaf(f[5].y, c.y, acc1);
            acc0 = fmaf(f[6].x, c.z, acc0); acc1 = fmaf(f[6].y, c.z, acc1);
            acc0 = fmaf(f[7].x, c.w, acc0); acc1 = fmaf(f[7].y, c.w, acc1);
            afg[0][k] = acc0; afg[1][k] = acc1;
        }
#pragma unroll
        for (int k = 0; k < KP; ++k) {
            const float4* pq = (const float4*)&pl[(KP + k) * CC + cbase + c0];
            float4 a = pq[0], c = pq[1];
            float acc0 = abg[0][k], acc1 = abg[1][k];
            acc0 = fmaf(f[0].x, a.x, acc0); acc1 = fmaf(f[0].y, a.x, acc1);
            acc0 = fmaf(f[1].x, a.y, acc0); acc1 = fmaf(f[1].y, a.y, acc1);
            acc0 = fmaf(f[2].x, a.z, acc0); acc1 = fmaf(f[2].y, a.z, acc1);
            acc0 = fmaf(f[3].x, a.w, acc0); acc1 = fmaf(f[3].y, a.w, acc1);
            acc0 = fmaf(f[4].x, c.x, acc0); acc1 = fmaf(f[4].y, c.x, acc1);
            acc0 = fmaf(f[5].x, c.y, acc0); acc1 = fmaf(f[5].y, c.y, acc1);
            acc0 = fmaf(f[6].x, c.z, acc0); acc1 = fmaf(f[6].y, c.z, acc1);
            acc0 = fmaf(f[7].x, c.w, acc0); acc1 = fmaf(f[7].y, c.w, acc1);
            abg[0][k] = acc0; abg[1][k] = acc1;
        }
#pragma unroll
        for (int j = 0; j < 8; ++j) {
            n2[0] = fmaf(f[j].x, f[j].x, n2[0]);
            n2[1] = fmaf(f[j].y, f[j].y, n2[1]);
        }
    }

    // fold 16 waves -> 8 slots
    if (w >= 8) {
#pragma unroll
        for (int px = 0; px < 2; ++px) {
#pragma unroll
            for (int k = 0; k < KP; ++k) {
                part[w - 8][lane][px][k]      = afg[px][k];
                part[w - 8][lane][px][10 + k] = abg[px][k];
            }
            part[w - 8][lane][px][20] = n2[px];
        }
    }
    __syncthreads();
    if (w < 8) {
#pragma unroll
        for (int px = 0; px < 2; ++px) {
#pragma unroll
            for (int k = 0; k < KP; ++k) {
                part[w][lane][px][k]      += afg[px][k];
                part[w][lane][px][10 + k] += abg[px][k];
            }
            part[w][lane][px][20] += n2[px];
        }
    }
    __syncthreads();

    // threads 0..127: finalize own pixel's two scores -> packed keys -> LDS
    if (tid < 128) {
        const int lane2 = tid >> 1, j = tid & 1;
        float vals[21];
#pragma unroll
        for (int q = 0; q < 21; ++q) {
            float acc = 0.f;
#pragma unroll
            for (int ss = 0; ss < 8; ++ss) acc += part[ss][lane2][j][q];
            vals[q] = acc;
        }
        float mfg = vals[0], mbg = vals[10];
#pragma unroll
        for (int k = 1; k < KP; ++k) { mfg = fmaxf(mfg, vals[k]); mbg = fmaxf(mbg, vals[10 + k]); }
        float nc = fmaxf(sqrtf(vals[20]), 1e-8f);
        int sp = b * 128 + tid;
        float m = fminf(fmaxf(M[sp], 0.f), 1.f);
        kfl[tid] = pack_key((1.f - mfg / nc) * m, sp);
        kbl[tid] = pack_key((1.f - mbg / nc) * (1.f - m), sp);
    }
    __syncthreads();

    // wave 0: fg top-12; wave 1: bg top-12. Pure in-wave butterflies, no barriers.
    if (w == 0) {
        ull k0 = kfl[lane], k1 = kfl[64 + lane];
        for (int r = 0; r < NS; ++r) {
            ull bk = (k0 > k1) ? k0 : k1;
#pragma unroll
            for (int m2 = 1; m2 < 64; m2 <<= 1) {
                ull o = __shfl_xor(bk, m2, 64);
                bk = (o > bk) ? o : bk;
            }
            if (lane == 0) cand[b * NS + r] = bk;
            if (k0 == bk) k0 = 0ull;
            if (k1 == bk) k1 = 0ull;
        }
    } else if (w == 1) {
        ull k0 = kbl[lane], k1 = kbl[64 + lane];
        for (int r = 0; r < NS; ++r) {
            ull bk = (k0 > k1) ? k0 : k1;
#pragma unroll
            for (int m2 = 1; m2 < 64; m2 <<= 1) {
                ull o = __shfl_xor(bk, m2, 64);
                bk = (o > bk) ? o : bk;
            }
            if (lane == 0) cand[NBLK * NS + b * NS + r] = bk;
            if (k0 == bk) k0 = 0ull;
            if (k1 == bk) k1 = 0ull;
        }
    }
}

// ---------------- K2: global top-12 merge + gather + normalize (2 blocks) ----
__global__ __launch_bounds__(1024) void k_topk2g(const ull* __restrict__ cand,
                                                 const float* __restrict__ F,
                                                 float* __restrict__ feats) {
    const int side = blockIdx.x;
    const int tid  = threadIdx.x;
    const int wave = __builtin_amdgcn_readfirstlane(tid >> 6);  // 0..15
    const int lane = tid & 63;

    __shared__ ull   wbest[16];
    __shared__ ull   win_sh;
    __shared__ int   seli[NS];
    __shared__ float gl[NS * CC];   // 36 KB

    const ull* cs = cand + side * (NBLK * NS);
    ull k0 = cs[tid];
    ull k1 = cs[1024 + tid];
    ull k2 = cs[2048 + tid];

    for (int r = 0; r < NS; ++r) {
        ull b = (k0 > k1) ? k0 : k1;
        b = (k2 > b) ? k2 : b;
#pragma unroll
        for (int m2 = 1; m2 < 64; m2 <<= 1) {
            ull o = __shfl_xor(b, m2, 64);
            b = (o > b) ? o : b;
        }
        if (lane == 0) wbest[wave] = b;
        __syncthreads();
        if (tid == 0) {
            ull m = wbest[0];
#pragma unroll
            for (int ww = 1; ww < 16; ++ww) m = (wbest[ww] > m) ? wbest[ww] : m;
            win_sh = m;
            seli[r] = (int)(0xFFFFFFFFu - (unsigned)(m & 0xFFFFFFFFull));
        }
        __syncthreads();
        ull win = win_sh;
        if (k0 == win) k0 = 0ull;
        if (k1 == win) k1 = 0ull;
        if (k2 == win) k2 = 0ull;
    }

    // gather 12 rows x 768 channels into LDS
    for (int i = tid; i < NS * CC; i += 1024) {
        int srow = i / CC, c = i - srow * CC;
        int sp = seli[srow];
        int nn = sp >> 12, hh = sp & 4095;
        gl[i] = F[((size_t)nn * CC + c) * HW + hh];
    }
    __syncthreads();

    // row-normalize: wave r (<12) handles row r; write to global feats
    if (wave < NS) {
        float ssq = 0.f;
#pragma unroll
        for (int j = 0; j < 12; ++j) { float v = gl[wave * CC + j * 64 + lane]; ssq = fmaf(v, v, ssq); }
#pragma unroll
        for (int m2 = 1; m2 < 64; m2 <<= 1) ssq += __shfl_xor(ssq, m2, 64);
        float inv = 1.f / fmaxf(sqrtf(ssq), 1e-8f);
#pragma unroll
        for (int j = 0; j < 12; ++j)
            feats[side * (NS * CC) + wave * CC + j * 64 + lane] = gl[wave * CC + j * 64 + lane] * inv;
    }
}

// ---------------- K3: refinement (one wave per prototype) + blend epilogue ----
// Lane l owns channels {j4*256 + 4l .. j4*256 + 4l+3} -> all LDS traffic is
// conflict-free ds_read_b128; proto load/store and out-blend are dwordx4.
__global__ __launch_bounds__(640) void k_refine(const float* __restrict__ feats_all,
                                                const float* __restrict__ fg,
                                                const float* __restrict__ bg,
                                                float* __restrict__ pfg,
                                                float* __restrict__ pbg,
                                                float* __restrict__ out) {
    __shared__ float fe[NS * CC];
    __shared__ float dots[NS][KP];
    __shared__ int   assign[NS];

    const int tid  = threadIdx.x;
    const int k    = __builtin_amdgcn_readfirstlane(tid >> 6);   // wave id = proto id
    const int lane = tid & 63;
    const float* feats = feats_all + blockIdx.x * (NS * CC);
    const float* p0    = (blockIdx.x == 0) ? fg : bg;
    float* pout        = (blockIdx.x == 0) ? pfg : pbg;

    for (int i = tid; i < NS * CC / 4; i += 640)
        ((float4*)fe)[i] = ((const float4*)feats)[i];
    float4 p[3];
#pragma unroll
    for (int j4 = 0; j4 < 3; ++j4)
        p[j4] = *(const float4*)&p0[k * CC + j4 * 256 + lane * 4];
    __syncthreads();

    for (int it = 0; it < 10; ++it) {
        float step = 0.1f / (1.0f + 0.5f * (float)it);

        float d[NS];
#pragma unroll
        for (int s = 0; s < NS; ++s) d[s] = 0.f;
#pragma unroll
        for (int j4 = 0; j4 < 3; ++j4) {
            float4 pv = p[j4];
#pragma unroll
            for (int s = 0; s < NS; ++s) {
                float4 fv = *(const float4*)&fe[s * CC + j4 * 256 + lane * 4];
                d[s] = fmaf(fv.x, pv.x, d[s]);
                d[s] = fmaf(fv.y, pv.y, d[s]);
                d[s] = fmaf(fv.z, pv.z, d[s]);
                d[s] = fmaf(fv.w, pv.w, d[s]);
            }
        }
#pragma unroll
        for (int s = 0; s < NS; ++s) {
#pragma unroll
            for (int m2 = 1; m2 < 64; m2 <<= 1) d[s] += __shfl_xor(d[s], m2, 64);
        }
        if (lane == 0) {
#pragma unroll
            for (int s = 0; s < NS; ++s) dots[s][k] = d[s];
        }
        __syncthreads();

        if (tid < NS) {
            float bv = dots[tid][0]; int bk = 0;
#pragma unroll
            for (int kk = 1; kk < KP; ++kk) { float v = dots[tid][kk]; if (v > bv) { bv = v; bk = kk; } }
            assign[tid] = bk;
        }
        __syncthreads();

        int a[NS]; int cnt = 0;
#pragma unroll
        for (int s = 0; s < NS; ++s) { a[s] = assign[s]; cnt += (a[s] == k) ? 1 : 0; }

        if (cnt > 0) {
            float4 mac[3];
#pragma unroll
            for (int j4 = 0; j4 < 3; ++j4) mac[j4] = make_float4(0.f, 0.f, 0.f, 0.f);
#pragma unroll
            for (int s = 0; s < NS; ++s) {
                if (a[s] == k) {   // wave-uniform branch
#pragma unroll
                    for (int j4 = 0; j4 < 3; ++j4) {
                        float4 fv = *(const float4*)&fe[s * CC + j4 * 256 + lane * 4];
                        mac[j4].x += fv.x; mac[j4].y += fv.y; mac[j4].z += fv.z; mac[j4].w += fv.w;
                    }
                }
            }
            float fcnt = (float)cnt;
            float4 v[3]; float ss = 0.f;
#pragma unroll
            for (int j4 = 0; j4 < 3; ++j4) {
                v[j4].x = (1.0f - step) * p[j4].x + step * (mac[j4].x / fcnt);
                v[j4].y = (1.0f - step) * p[j4].y + step * (mac[j4].y / fcnt);
                v[j4].z = (1.0f - step) * p[j4].z + step * (mac[j4].z / fcnt);
                v[j4].w = (1.0f - step) * p[j4].w + step * (mac[j4].w / fcnt);
                ss = fmaf(v[j4].x, v[j4].x, ss);
                ss = fmaf(v[j4].y, v[j4].y, ss);
                ss = fmaf(v[j4].z, v[j4].z, ss);
                ss = fmaf(v[j4].w, v[j4].w, ss);
            }
#pragma unroll
            for (int m2 = 1; m2 < 64; m2 <<= 1) ss += __shfl_xor(ss, m2, 64);
            float inv = 1.f / fmaxf(sqrtf(ss), 1e-8f);
#pragma unroll
            for (int j4 = 0; j4 < 3; ++j4) {
                p[j4].x = v[j4].x * inv; p[j4].y = v[j4].y * inv;
                p[j4].z = v[j4].z * inv; p[j4].w = v[j4].w * inv;
            }
        }
    }

    // publish refined protos for the loss kernel (dwordx4, coalesced)
#pragma unroll
    for (int j4 = 0; j4 < 3; ++j4)
        *(float4*)&pout[k * CC + j4 * 256 + lane * 4] = p[j4];

    // blend epilogue: out row = safe_norm(0.7*p0 + 0.3*p)
    float4 vv[3]; float ss2 = 0.f;
#pragma unroll
    for (int j4 = 0; j4 < 3; ++j4) {
        float4 pz = *(const float4*)&p0[k * CC + j4 * 256 + lane * 4];
        vv[j4].x = 0.7f * pz.x + 0.3f * p[j4].x;
        vv[j4].y = 0.7f * pz.y + 0.3f * p[j4].y;
        vv[j4].z = 0.7f * pz.z + 0.3f * p[j4].z;
        vv[j4].w = 0.7f * pz.w + 0.3f * p[j4].w;
        ss2 = fmaf(vv[j4].x, vv[j4].x, ss2);
        ss2 = fmaf(vv[j4].y, vv[j4].y, ss2);
        ss2 = fmaf(vv[j4].z, vv[j4].z, ss2);
        ss2 = fmaf(vv[j4].w, vv[j4].w, ss2);
    }
#pragma unroll
    for (int m2 = 1; m2 < 64; m2 <<= 1) ss2 += __shfl_xor(ss2, m2, 64);
    float inv2 = 1.f / fmaxf(sqrtf(ss2), 1e-8f);
    float* orow = out + 1 + (blockIdx.x * KP + k) * CC;
#pragma unroll
    for (int j4 = 0; j4 < 3; ++j4) {
        float4 o4;
        o4.x = vv[j4].x * inv2; o4.y = vv[j4].y * inv2;
        o4.z = vv[j4].z * inv2; o4.w = vv[j4].w * inv2;
        *(float4*)&orow[j4 * 256 + lane * 4] = o4;
    }
}

// ---------------- K4: loss (1 block) ----------------
__global__ __launch_bounds__(256) void k_loss(const float* __restrict__ feats,
                                              const float* __restrict__ pfg,
                                              const float* __restrict__ pbg,
                                              float* __restrict__ out) {
    __shared__ float dots3[NS * 30];   // [s][g*10+k]: g=0 pos@pfg, g=1 neg@pfg, g=2 pos@pbg
    __shared__ float mp[NS], mn[NS], infon[NS];
    int tid = threadIdx.x, wave = tid >> 6, lane = tid & 63;

    for (int pid = wave; pid < 360; pid += 4) {
        int g = pid / 120, rr = pid % 120, s = rr / KP, k = rr % KP;
        const float4* a4 = (const float4*)(feats + ((g == 1 ? NS + s : s) * CC) + lane * 12);
        const float4* b4 = (const float4*)((g == 2 ? pbg : pfg) + k * CC + lane * 12);
        float acc = 0.f;
#pragma unroll
        for (int j = 0; j < 3; ++j) {
            float4 a = a4[j], b = b4[j];
            acc += a.x * b.x + a.y * b.y + a.z * b.z + a.w * b.w;
        }
#pragma unroll
        for (int m2 = 1; m2 < 64; m2 <<= 1) acc += __shfl_xor(acc, m2, 64);
        if (lane == 0) dots3[s * 30 + g * 10 + k] = acc;
    }
    __syncthreads();

    if (tid < NS) {
        const float* d = &dots3[tid * 30];
        float maxp = d[0], maxn = d[10];
#pragma unroll
        for (int k = 1; k < KP; ++k) { maxp = fmaxf(maxp, d[k]); maxn = fmaxf(maxn, d[10 + k]); }
        mp[tid] = maxp; mn[tid] = maxn;

        float x[KP], y[KP];
#pragma unroll
        for (int k = 0; k < KP; ++k) { x[k] = d[k] / 0.07f; y[k] = d[20 + k] / 0.07f; }
        float m10 = x[0];
#pragma unroll
        for (int k = 1; k < KP; ++k) m10 = fmaxf(m10, x[k]);
        float se = 0.f;
#pragma unroll
        for (int k = 0; k < KP; ++k) se += expf(x[k] - m10);
        float numer = logf(se) + m10;
        float m20 = m10;
#pragma unroll
        for (int k = 0; k < KP; ++k) m20 = fmaxf(m20, y[k]);
        float se2 = 0.f;
#pragma unroll
        for (int k = 0; k < KP; ++k) se2 += expf(x[k] - m20);
#pragma unroll
        for (int k = 0; k < KP; ++k) se2 += expf(y[k] - m20);
        float denom = logf(se2) + m20;
        infon[tid] = numer - denom;
    }
    __syncthreads();
    if (tid == 0) {
        float sp = 0.f, sn = 0.f, si = 0.f;
        for (int s = 0; s < NS; ++s) { sp += mp[s]; sn += mn[s]; si += infon[s]; }
        sp /= 12.f; sn /= 12.f; si /= 12.f;
        float loss = fmaxf(0.2f + sn - sp, 0.f) + 0.25f * (-si);
        out[0] = loss;
    }
}

extern "C" void kernel_launch(void* const* d_in, const int* in_sizes, int n_in,
                              void* d_out, int out_size, void* d_ws, size_t ws_size,
                              hipStream_t stream) {
    const float* fg = (const float*)d_in[0];   // [10,768]
    const float* bg = (const float*)d_in[1];   // [10,768]
    const float* F  = (const float*)d_in[2];   // [8,768,64,64]
    const float* M  = (const float*)d_in[3];   // [8,1,64,64]
    float* out = (float*)d_out;                // [1 + 7680 + 7680]

    float* w    = (float*)d_ws;
    ull*   cand = (ull*)(w + WS_CAND);
    float* fea  = w + WS_FEATS;
    float* pfg  = w + WS_PFG;
    float* pbg  = w + WS_PBG;

    k_scores<<<NBLK, 1024, 0, stream>>>(fg, bg, F, M, cand);
    k_topk2g<<<2, 1024, 0, stream>>>(cand, F, fea);
    k_refine<<<2, 640, 0, stream>>>(fea, fg, bg, pfg, pbg, out);
    k_loss  <<<1, 256, 0, stream>>>(fea, pfg, pbg, out);
}

// Round 13
// 125.905 us; speedup vs baseline: 1.3432x; 1.1625x over previous
//
#include <hip/hip_runtime.h>
#include <math.h>

// Problem constants
#define KP   10      // prototypes per side
#define CC   768     // channels
#define NB   8       // batch
#define HW   4096    // 64*64
#define STOT 32768   // NB*HW
#define NS   12      // N_SAMPLES
#define NBLK 256     // k_scores blocks (128 px each)

// Workspace layout (float offsets)
#define WS_CAND  0       // 2 sides x 256 blocks x 12 u64 = 6144 ull = 12288 floats
#define WS_FEATS 12352   // 24*768 floats (pos 12 rows, then neg 12 rows)
#define WS_PFG   30784   // 10*768
#define WS_PBG   38464   // 10*768

typedef unsigned long long ull;
typedef float f2v __attribute__((ext_vector_type(2)));

// packed 2-wide fma (v_pk_fma_f32); per-component order identical to scalar fmaf
__device__ __forceinline__ f2v fma2(f2v a, float b, f2v c) {
#if __has_builtin(__builtin_elementwise_fma)
    f2v bb = b;
    return __builtin_elementwise_fma(a, bb, c);
#else
    f2v r; r.x = fmaf(a.x, b, c.x); r.y = fmaf(a.y, b, c.y); return r;
#endif
}

// Order-preserving float->uint map, packed with ~index: exact
// (value desc, index asc) under unsigned max; unique per pixel; 0 = empty.
__device__ __forceinline__ ull pack_key(float v, int idx) {
    unsigned u = __float_as_uint(v);
    u ^= (unsigned)((int)u >> 31) | 0x80000000u;
    return ((ull)u << 32) | (ull)(0xFFFFFFFFu - (unsigned)idx);
}

// ---------------- K1: scores + per-block top-12 candidates ----------------
// 1024 threads: 16 waves x 48 channels; 2 px/lane (dwordx2 nt F loads,
// depth-2 prefetch). Protos in LDS. Packed-f32 dot accumulators.
// Selection: keys to LDS, wave 0 (fg) / wave 1 (bg) barrier-free butterflies.
__global__ __launch_bounds__(1024) void k_scores(const float* __restrict__ fg,
                                                 const float* __restrict__ bg,
                                                 const float* __restrict__ F,
                                                 const float* __restrict__ M,
                                                 ull* __restrict__ cand) {
    __shared__ float pl[20 * CC];           // 61440 B
    __shared__ float part[8][64][2][21];    // 86016 B
    __shared__ ull kfl[128], kbl[128];      // 2048 B

    const int tid  = threadIdx.x;
    const int w    = __builtin_amdgcn_readfirstlane(tid >> 6);  // wave 0..15
    const int lane = tid & 63;
    const int b    = blockIdx.x;            // 0..255
    const int n    = b >> 5;                // 32 blocks per image
    const int hwb  = (b & 31) * 128 + lane * 2;
    const float* fp = F + ((size_t)n * CC) * HW + hwb;
    const int cbase = w * 48;

    // depth-2 prefetch (independent of LDS staging)
    f2v fnA[8], fnB[8];
#pragma unroll
    for (int j = 0; j < 8; ++j)
        fnA[j] = __builtin_nontemporal_load((const f2v*)(fp + (size_t)(cbase + j) * HW));
#pragma unroll
    for (int j = 0; j < 8; ++j)
        fnB[j] = __builtin_nontemporal_load((const f2v*)(fp + (size_t)(cbase + 8 + j) * HW));

    for (int i = tid; i < KP * CC; i += 1024) {
        pl[i]           = fg[i];
        pl[KP * CC + i] = bg[i];
    }
    __syncthreads();

    f2v afg[KP], abg[KP], n2;
#pragma unroll
    for (int k = 0; k < KP; ++k) { afg[k] = 0.f; abg[k] = 0.f; }
    n2 = 0.f;

    for (int c0 = 0; c0 < 48; c0 += 8) {
        f2v f[8];
#pragma unroll
        for (int j = 0; j < 8; ++j) { f[j] = fnA[j]; fnA[j] = fnB[j]; }
        if (c0 + 16 < 48) {
#pragma unroll
            for (int j = 0; j < 8; ++j)
                fnB[j] = __builtin_nontemporal_load((const f2v*)(fp + (size_t)(cbase + c0 + 16 + j) * HW));
        }

#pragma unroll
        for (int k = 0; k < KP; ++k) {
            const float4* pq = (const float4*)&pl[k * CC + cbase + c0];
            float4 a = pq[0], c = pq[1];
            f2v acc = afg[k];
            acc = fma2(f[0], a.x, acc); acc = fma2(f[1], a.y, acc);
            acc = fma2(f[2], a.z, acc); acc = fma2(f[3], a.w, acc);
            acc = fma2(f[4], c.x, acc); acc = fma2(f[5], c.y, acc);
            acc = fma2(f[6], c.z, acc); acc = fma2(f[7], c.w, acc);
            afg[k] = acc;
        }
#pragma unroll
        for (int k = 0; k < KP; ++k) {
            const float4* pq = (const float4*)&pl[(KP + k) * CC + cbase + c0];
            float4 a = pq[0], c = pq[1];
            f2v acc = abg[k];
            acc = fma2(f[0], a.x, acc); acc = fma2(f[1], a.y, acc);
            acc = fma2(f[2], a.z, acc); acc = fma2(f[3], a.w, acc);
            acc = fma2(f[4], c.x, acc); acc = fma2(f[5], c.y, acc);
            acc = fma2(f[6], c.z, acc); acc = fma2(f[7], c.w, acc);
            abg[k] = acc;
        }
#pragma unroll
        for (int j = 0; j < 8; ++j) {
#if __has_builtin(__builtin_elementwise_fma)
            n2 = __builtin_elementwise_fma(f[j], f[j], n2);
#else
            n2.x = fmaf(f[j].x, f[j].x, n2.x); n2.y = fmaf(f[j].y, f[j].y, n2.y);
#endif
        }
    }

    // fold 16 waves -> 8 slots
    if (w >= 8) {
#pragma unroll
        for (int k = 0; k < KP; ++k) {
            part[w - 8][lane][0][k]      = afg[k].x; part[w - 8][lane][1][k]      = afg[k].y;
            part[w - 8][lane][0][10 + k] = abg[k].x; part[w - 8][lane][1][10 + k] = abg[k].y;
        }
        part[w - 8][lane][0][20] = n2.x; part[w - 8][lane][1][20] = n2.y;
    }
    __syncthreads();
    if (w < 8) {
#pragma unroll
        for (int k = 0; k < KP; ++k) {
            part[w][lane][0][k]      += afg[k].x; part[w][lane][1][k]      += afg[k].y;
            part[w][lane][0][10 + k] += abg[k].x; part[w][lane][1][10 + k] += abg[k].y;
        }
        part[w][lane][0][20] += n2.x; part[w][lane][1][20] += n2.y;
    }
    __syncthreads();

    // threads 0..127: finalize own pixel's two scores -> packed keys -> LDS
    if (tid < 128) {
        const int lane2 = tid >> 1, j = tid & 1;
        float vals[21];
#pragma unroll
        for (int q = 0; q < 21; ++q) {
            float acc = 0.f;
#pragma unroll
            for (int ss = 0; ss < 8; ++ss) acc += part[ss][lane2][j][q];
            vals[q] = acc;
        }
        float mfg = vals[0], mbg = vals[10];
#pragma unroll
        for (int k = 1; k < KP; ++k) { mfg = fmaxf(mfg, vals[k]); mbg = fmaxf(mbg, vals[10 + k]); }
        float nc = fmaxf(sqrtf(vals[20]), 1e-8f);
        int sp = b * 128 + tid;
        float m = fminf(fmaxf(M[sp], 0.f), 1.f);
        kfl[tid] = pack_key((1.f - mfg / nc) * m, sp);
        kbl[tid] = pack_key((1.f - mbg / nc) * (1.f - m), sp);
    }
    __syncthreads();

    // wave 0: fg top-12; wave 1: bg top-12. Barrier-free in-wave butterflies.
    if (w == 0) {
        ull k0 = kfl[lane], k1 = kfl[64 + lane];
        for (int r = 0; r < NS; ++r) {
            ull bk = (k0 > k1) ? k0 : k1;
#pragma unroll
            for (int m2 = 1; m2 < 64; m2 <<= 1) {
                ull o = __shfl_xor(bk, m2, 64);
                bk = (o > bk) ? o : bk;
            }
            if (lane == 0) cand[b * NS + r] = bk;
            if (k0 == bk) k0 = 0ull;
            if (k1 == bk) k1 = 0ull;
        }
    } else if (w == 1) {
        ull k0 = kbl[lane], k1 = kbl[64 + lane];
        for (int r = 0; r < NS; ++r) {
            ull bk = (k0 > k1) ? k0 : k1;
#pragma unroll
            for (int m2 = 1; m2 < 64; m2 <<= 1) {
                ull o = __shfl_xor(bk, m2, 64);
                bk = (o > bk) ? o : bk;
            }
            if (lane == 0) cand[NBLK * NS + b * NS + r] = bk;
            if (k0 == bk) k0 = 0ull;
            if (k1 == bk) k1 = 0ull;
        }
    }
}

// ---- K2: fused global top-12 merge + gather + normalize + refine + blend ----
// One 1024-thread block per side. Merge: wave 0 only, barrier-free (48 keys/
// lane -> per-lane sorted top-12 regs -> 12 butterfly rounds). Then gather to
// LDS, row-normalize, publish feats, refine (waves 0..9 = protos), blend out.
__global__ __launch_bounds__(1024) void k_refine_fused(const ull* __restrict__ cand,
                                                       const float* __restrict__ F,
                                                       const float* __restrict__ fg,
                                                       const float* __restrict__ bg,
                                                       float* __restrict__ pfg,
                                                       float* __restrict__ pbg,
                                                       float* __restrict__ feats,
                                                       float* __restrict__ out) {
    __shared__ float fe[NS * CC];   // 36 KB
    __shared__ int   seli[NS];
    __shared__ float dots[NS][KP];
    __shared__ int   assign[NS];

    const int side = blockIdx.x;
    const int tid  = threadIdx.x;
    const int wave = __builtin_amdgcn_readfirstlane(tid >> 6);  // 0..15
    const int lane = tid & 63;
    const int k    = wave;                                       // proto id for waves<KP
    const float* p0 = (side == 0) ? fg : bg;
    float* pout     = (side == 0) ? pfg : pbg;

    // ---- merge: wave 0 only, no barriers ----
    if (wave == 0) {
        const ull* cs = cand + side * (NBLK * NS);
        ull tv[NS];
#pragma unroll
        for (int q = 0; q < NS; ++q) tv[q] = 0ull;
        for (int c = 0; c < 48; ++c) {               // 3072 keys / 64 lanes
            ull key = cs[c * 64 + lane];
            if (key > tv[NS - 1]) {
#pragma unroll
                for (int q = NS - 1; q >= 1; --q) {
                    bool shift = key > tv[q - 1];
                    bool here  = !shift && (key > tv[q]);
                    tv[q] = shift ? tv[q - 1] : (here ? key : tv[q]);
                }
                if (key > tv[0]) tv[0] = key;
            }
        }
        for (int r = 0; r < NS; ++r) {
            ull bk = tv[0];
#pragma unroll
            for (int m2 = 1; m2 < 64; m2 <<= 1) {
                ull o = __shfl_xor(bk, m2, 64);
                bk = (o > bk) ? o : bk;
            }
            if (lane == 0) seli[r] = (int)(0xFFFFFFFFu - (unsigned)(bk & 0xFFFFFFFFull));
            bool win = (tv[0] == bk);                // keys unique -> exactly one lane
#pragma unroll
            for (int q = 0; q < NS - 1; ++q) tv[q] = win ? tv[q + 1] : tv[q];
            tv[NS - 1] = win ? 0ull : tv[NS - 1];
        }
    }
    __syncthreads();

    // ---- gather 12 rows x 768 channels into LDS ----
    for (int i = tid; i < NS * CC; i += 1024) {
        int srow = i / CC, c = i - srow * CC;
        int sp = seli[srow];
        int nn = sp >> 12, hh = sp & 4095;
        fe[i] = F[((size_t)nn * CC + c) * HW + hh];
    }
    __syncthreads();

    // ---- row-normalize in place: wave r handles row r ----
    if (wave < NS) {
        float ssq = 0.f;
#pragma unroll
        for (int j = 0; j < 12; ++j) { float v = fe[wave * CC + j * 64 + lane]; ssq = fmaf(v, v, ssq); }
#pragma unroll
        for (int m2 = 1; m2 < 64; m2 <<= 1) ssq += __shfl_xor(ssq, m2, 64);
        float inv = 1.f / fmaxf(sqrtf(ssq), 1e-8f);
#pragma unroll
        for (int j = 0; j < 12; ++j) fe[wave * CC + j * 64 + lane] *= inv;
    }
    __syncthreads();

    // ---- publish normalized feats for k_loss (coalesced b128) ----
    {
        float4* fo = (float4*)(feats + side * (NS * CC));
        const float4* fi = (const float4*)fe;
        for (int i = tid; i < NS * CC / 4; i += 1024) fo[i] = fi[i];
    }

    // ---- refinement: waves 0..9 own proto k; all waves hit barriers ----
    float4 p[3];
#pragma unroll
    for (int j4 = 0; j4 < 3; ++j4) p[j4] = make_float4(0.f, 0.f, 0.f, 0.f);
    if (wave < KP) {
#pragma unroll
        for (int j4 = 0; j4 < 3; ++j4)
            p[j4] = *(const float4*)&p0[k * CC + j4 * 256 + lane * 4];
    }

    for (int it = 0; it < 10; ++it) {
        float step = 0.1f / (1.0f + 0.5f * (float)it);

        if (wave < KP) {
            float d[NS];
#pragma unroll
            for (int s = 0; s < NS; ++s) d[s] = 0.f;
#pragma unroll
            for (int j4 = 0; j4 < 3; ++j4) {
                float4 pv = p[j4];
#pragma unroll
                for (int s = 0; s < NS; ++s) {
                    float4 fv = *(const float4*)&fe[s * CC + j4 * 256 + lane * 4];
                    d[s] = fmaf(fv.x, pv.x, d[s]);
                    d[s] = fmaf(fv.y, pv.y, d[s]);
                    d[s] = fmaf(fv.z, pv.z, d[s]);
                    d[s] = fmaf(fv.w, pv.w, d[s]);
                }
            }
#pragma unroll
            for (int s = 0; s < NS; ++s) {
#pragma unroll
                for (int m2 = 1; m2 < 64; m2 <<= 1) d[s] += __shfl_xor(d[s], m2, 64);
            }
            if (lane == 0) {
#pragma unroll
                for (int s = 0; s < NS; ++s) dots[s][k] = d[s];
            }
        }
        __syncthreads();

        if (tid < NS) {
            float bv = dots[tid][0]; int bk = 0;
#pragma unroll
            for (int kk = 1; kk < KP; ++kk) { float v = dots[tid][kk]; if (v > bv) { bv = v; bk = kk; } }
            assign[tid] = bk;
        }
        __syncthreads();

        if (wave < KP) {
            int a[NS]; int cnt = 0;
#pragma unroll
            for (int s = 0; s < NS; ++s) { a[s] = assign[s]; cnt += (a[s] == k) ? 1 : 0; }

            if (cnt > 0) {
                float4 mac[3];
#pragma unroll
                for (int j4 = 0; j4 < 3; ++j4) mac[j4] = make_float4(0.f, 0.f, 0.f, 0.f);
#pragma unroll
                for (int s = 0; s < NS; ++s) {
                    if (a[s] == k) {   // wave-uniform branch
#pragma unroll
                        for (int j4 = 0; j4 < 3; ++j4) {
                            float4 fv = *(const float4*)&fe[s * CC + j4 * 256 + lane * 4];
                            mac[j4].x += fv.x; mac[j4].y += fv.y; mac[j4].z += fv.z; mac[j4].w += fv.w;
                        }
                    }
                }
                float fcnt = (float)cnt;
                float4 v[3]; float ss = 0.f;
#pragma unroll
                for (int j4 = 0; j4 < 3; ++j4) {
                    v[j4].x = (1.0f - step) * p[j4].x + step * (mac[j4].x / fcnt);
                    v[j4].y = (1.0f - step) * p[j4].y + step * (mac[j4].y / fcnt);
                    v[j4].z = (1.0f - step) * p[j4].z + step * (mac[j4].z / fcnt);
                    v[j4].w = (1.0f - step) * p[j4].w + step * (mac[j4].w / fcnt);
                    ss = fmaf(v[j4].x, v[j4].x, ss);
                    ss = fmaf(v[j4].y, v[j4].y, ss);
                    ss = fmaf(v[j4].z, v[j4].z, ss);
                    ss = fmaf(v[j4].w, v[j4].w, ss);
                }
#pragma unroll
                for (int m2 = 1; m2 < 64; m2 <<= 1) ss += __shfl_xor(ss, m2, 64);
                float inv = 1.f / fmaxf(sqrtf(ss), 1e-8f);
#pragma unroll
                for (int j4 = 0; j4 < 3; ++j4) {
                    p[j4].x = v[j4].x * inv; p[j4].y = v[j4].y * inv;
                    p[j4].z = v[j4].z * inv; p[j4].w = v[j4].w * inv;
                }
            }
        }
    }

    if (wave < KP) {
        // publish refined protos for the loss kernel
#pragma unroll
        for (int j4 = 0; j4 < 3; ++j4)
            *(float4*)&pout[k * CC + j4 * 256 + lane * 4] = p[j4];

        // blend epilogue: out row = safe_norm(0.7*p0 + 0.3*p)
        float4 vv[3]; float ss2 = 0.f;
#pragma unroll
        for (int j4 = 0; j4 < 3; ++j4) {
            float4 pz = *(const float4*)&p0[k * CC + j4 * 256 + lane * 4];
            vv[j4].x = 0.7f * pz.x + 0.3f * p[j4].x;
            vv[j4].y = 0.7f * pz.y + 0.3f * p[j4].y;
            vv[j4].z = 0.7f * pz.z + 0.3f * p[j4].z;
            vv[j4].w = 0.7f * pz.w + 0.3f * p[j4].w;
            ss2 = fmaf(vv[j4].x, vv[j4].x, ss2);
            ss2 = fmaf(vv[j4].y, vv[j4].y, ss2);
            ss2 = fmaf(vv[j4].z, vv[j4].z, ss2);
            ss2 = fmaf(vv[j4].w, vv[j4].w, ss2);
        }
#pragma unroll
        for (int m2 = 1; m2 < 64; m2 <<= 1) ss2 += __shfl_xor(ss2, m2, 64);
        float inv2 = 1.f / fmaxf(sqrtf(ss2), 1e-8f);
        float* orow = out + 1 + (side * KP + k) * CC;
#pragma unroll
        for (int j4 = 0; j4 < 3; ++j4) {
            float4 o4;
            o4.x = vv[j4].x * inv2; o4.y = vv[j4].y * inv2;
            o4.z = vv[j4].z * inv2; o4.w = vv[j4].w * inv2;
            *(float4*)&orow[j4 * 256 + lane * 4] = o4;
        }
    }
}

// ---------------- K3: loss (1 block, 16 waves) ----------------
__global__ __launch_bounds__(1024) void k_loss(const float* __restrict__ feats,
                                               const float* __restrict__ pfg,
                                               const float* __restrict__ pbg,
                                               float* __restrict__ out) {
    __shared__ float dots3[NS * 30];   // [s][g*10+k]: g=0 pos@pfg, g=1 neg@pfg, g=2 pos@pbg
    __shared__ float mp[NS], mn[NS], infon[NS];
    int tid = threadIdx.x, wave = tid >> 6, lane = tid & 63;

    for (int pid = wave; pid < 360; pid += 16) {
        int g = pid / 120, rr = pid % 120, s = rr / KP, k = rr % KP;
        const float4* a4 = (const float4*)(feats + ((g == 1 ? NS + s : s) * CC) + lane * 12);
        const float4* b4 = (const float4*)((g == 2 ? pbg : pfg) + k * CC + lane * 12);
        float acc = 0.f;
#pragma unroll
        for (int j = 0; j < 3; ++j) {
            float4 a = a4[j], b = b4[j];
            acc += a.x * b.x + a.y * b.y + a.z * b.z + a.w * b.w;
        }
#pragma unroll
        for (int m2 = 1; m2 < 64; m2 <<= 1) acc += __shfl_xor(acc, m2, 64);
        if (lane == 0) dots3[s * 30 + g * 10 + k] = acc;
    }
    __syncthreads();

    if (tid < NS) {
        const float* d = &dots3[tid * 30];
        float maxp = d[0], maxn = d[10];
#pragma unroll
        for (int k = 1; k < KP; ++k) { maxp = fmaxf(maxp, d[k]); maxn = fmaxf(maxn, d[10 + k]); }
        mp[tid] = maxp; mn[tid] = maxn;

        float x[KP], y[KP];
#pragma unroll
        for (int k = 0; k < KP; ++k) { x[k] = d[k] / 0.07f; y[k] = d[20 + k] / 0.07f; }
        float m10 = x[0];
#pragma unroll
        for (int k = 1; k < KP; ++k) m10 = fmaxf(m10, x[k]);
        float se = 0.f;
#pragma unroll
        for (int k = 0; k < KP; ++k) se += expf(x[k] - m10);
        float numer = logf(se) + m10;
        float m20 = m10;
#pragma unroll
        for (int k = 0; k < KP; ++k) m20 = fmaxf(m20, y[k]);
        float se2 = 0.f;
#pragma unroll
        for (int k = 0; k < KP; ++k) se2 += expf(x[k] - m20);
#pragma unroll
        for (int k = 0; k < KP; ++k) se2 += expf(y[k] - m20);
        float denom = logf(se2) + m20;
        infon[tid] = numer - denom;
    }
    __syncthreads();
    if (tid == 0) {
        float sp = 0.f, sn = 0.f, si = 0.f;
        for (int s = 0; s < NS; ++s) { sp += mp[s]; sn += mn[s]; si += infon[s]; }
        sp /= 12.f; sn /= 12.f; si /= 12.f;
        float loss = fmaxf(0.2f + sn - sp, 0.f) + 0.25f * (-si);
        out[0] = loss;
    }
}

extern "C" void kernel_launch(void* const* d_in, const int* in_sizes, int n_in,
                              void* d_out, int out_size, void* d_ws, size_t ws_size,
                              hipStream_t stream) {
    const float* fg = (const float*)d_in[0];   // [10,768]
    const float* bg = (const float*)d_in[1];   // [10,768]
    const float* F  = (const float*)d_in[2];   // [8,768,64,64]
    const float* M  = (const float*)d_in[3];   // [8,1,64,64]
    float* out = (float*)d_out;                // [1 + 7680 + 7680]

    float* w    = (float*)d_ws;
    ull*   cand = (ull*)(w + WS_CAND);
    float* fea  = w + WS_FEATS;
    float* pfg  = w + WS_PFG;
    float* pbg  = w + WS_PBG;

    k_scores      <<<NBLK, 1024, 0, stream>>>(fg, bg, F, M, cand);
    k_refine_fused<<<2, 1024, 0, stream>>>(cand, F, fg, bg, pfg, pbg, fea, out);
    k_loss        <<<1, 1024, 0, stream>>>(fea, pfg, pbg, out);
}